// Round 5
// baseline (200.284 us; speedup 1.0000x reference)
//
#include <hip/hip_runtime.h>

// VQ embedding, bf16-MFMA, occupancy-first (4 waves/SIMD target).
// z: (B=64, D=256, H=32, W=32) fp32; codebook: (K=1024, D=256) fp32.
// Trick: stage A = -2z (bf16, exact scaling), init acc = 1 + ||c_k||^2 (per-lane column
// broadcast) -> MFMA output IS the shifted score 1 + ||c||^2 - 2 z.c > 0.
// Packed key (score_bits & 0xFFFFFC00) | k -> uint min = argmin with first-index ties.
// Outputs (flat fp32): st[16777216] = chosen codebook row, indices[65536] as float,
// loss = 1.25 * (sum z^2 + sum (best_score - 1)).

#define IDX_OFF  16777216
#define LOSS_OFF 16842752

typedef __bf16 bf16x8 __attribute__((ext_vector_type(8)));
typedef float  f32x4  __attribute__((ext_vector_type(4)));

// ---- Kernel 1: cb fp32 -> TRANSPOSED bf16 cbh[c][k][32] (c = d>>5), sc1[k] = 1+||c||^2,
//      and zero the loss accumulator (merged memset). 64 blocks.
__global__ __launch_bounds__(256) void vq_prep(const float* __restrict__ cb,
                                               __bf16* __restrict__ cbh,
                                               float* __restrict__ sc1,
                                               float* __restrict__ out) {
    if (blockIdx.x == 0 && threadIdx.x == 0) out[LOSS_OFF] = 0.f;
    const int t = threadIdx.x;
    const int r = blockIdx.x * 16 + (t >> 4);
    const int d0 = (t & 15) * 16;
    const float* src = cb + (size_t)r * 256 + d0;
    float s = 0.f;
    float4 f[4];
    #pragma unroll
    for (int p = 0; p < 4; p++) f[p] = *(const float4*)(src + p * 4);
    #pragma unroll
    for (int p = 0; p < 4; p++) {
        s = fmaf(f[p].x, f[p].x, s); s = fmaf(f[p].y, f[p].y, s);
        s = fmaf(f[p].z, f[p].z, s); s = fmaf(f[p].w, f[p].w, s);
    }
    bf16x8 v0, v1;
    v0[0]=(__bf16)f[0].x; v0[1]=(__bf16)f[0].y; v0[2]=(__bf16)f[0].z; v0[3]=(__bf16)f[0].w;
    v0[4]=(__bf16)f[1].x; v0[5]=(__bf16)f[1].y; v0[6]=(__bf16)f[1].z; v0[7]=(__bf16)f[1].w;
    v1[0]=(__bf16)f[2].x; v1[1]=(__bf16)f[2].y; v1[2]=(__bf16)f[2].z; v1[3]=(__bf16)f[2].w;
    v1[4]=(__bf16)f[3].x; v1[5]=(__bf16)f[3].y; v1[6]=(__bf16)f[3].z; v1[7]=(__bf16)f[3].w;
    // transposed: chunk c = d0>>5 (d0&31 in {0,16})
    __bf16* dst = cbh + (size_t)(d0 >> 5) * 32768 + r * 32 + (d0 & 31);
    *(bf16x8*)dst = v0;
    *(bf16x8*)(dst + 8) = v1;
    s += __shfl_xor(s, 1, 64);
    s += __shfl_xor(s, 2, 64);
    s += __shfl_xor(s, 4, 64);
    s += __shfl_xor(s, 8, 64);
    if ((t & 15) == 0) sc1[r] = s + 1.0f;
}

// ---- Kernel 2: MFMA distance-GEMM + argmin + outputs. Block = 64 n-rows, all 1024 codes.
// 4 waves: wn = (w>>1)*32 rows, wk = (w&1)*64 codes of each 128-wide kt step.
// LDS 32 KB: -2z tile [64][256] bf16 XOR-swizzled; recycled as argmin scratch then q tile.
// No barriers in K-loop; A (LDS) and B (L2, transposed) both depth-1 register-pipelined.
__global__ __launch_bounds__(256, 4) void vq_mfma(const float* __restrict__ z,
                                                  const float* __restrict__ cb,
                                                  const __bf16* __restrict__ cbh,
                                                  const float* __restrict__ sc1,
                                                  float* __restrict__ out) {
    __shared__ __align__(16) __bf16 z_s[64 * 256];   // 32768 B
    __shared__ float red_s[4];

    const int t    = threadIdx.x;
    const int lane = t & 63;
    const int w    = t >> 6;
    const int m16  = lane & 15;
    const int q4   = lane >> 4;
    const int wn   = (w >> 1) * 32;
    const int wk   = (w & 1) * 64;
    const int blk  = blockIdx.x;
    const int b    = blk >> 4;
    const int hw0  = (blk & 15) << 6;
    const int n0   = blk << 6;

    // per-lane transposed-B base: addr(kts,c,j) = c*32768 + (kts*128 + wk + j*16 + m16)*32 + q4*8
    const __bf16* bbase = cbh + (size_t)(wk + m16) * 32 + q4 * 8;

    // preload kt=0: sck and chunk-0 B frags (in flight under phase A)
    float sck[4];
    #pragma unroll
    for (int j = 0; j < 4; j++) sck[j] = sc1[wk + j * 16 + m16];
    bf16x8 bb[4];
    #pragma unroll
    for (int j = 0; j < 4; j++) bb[j] = *(const bf16x8*)(bbase + j * 512);

    // ---- phase A: stage -2z (bf16) into LDS [n][d], swizzled; accumulate sum z^2
    float lz = 0.f;
    {
        const int nl = t & 63;
        const int dq = (t >> 6) << 6;   // 0,64,128,192
        const float* zp = z + (size_t)(b * 256 + dq) * 1024 + hw0 + nl;
        #pragma unroll
        for (int p = 0; p < 8; p++) {
            bf16x8 v;
            #pragma unroll
            for (int j = 0; j < 8; j++) {
                float f = zp[(size_t)(p * 8 + j) * 1024];
                lz = fmaf(f, f, lz);
                v[j] = (__bf16)(-2.0f * f);
            }
            int gs = ((dq >> 3) + p) ^ (nl & 7);
            *(bf16x8*)&z_s[nl * 256 + gs * 8] = v;
        }
    }
    __syncthreads();

    // preload chunk-0 A frags
    bf16x8 a[2];
    #pragma unroll
    for (int i = 0; i < 2; i++) {
        int gs = q4 ^ (m16 & 7);
        a[i] = *(const bf16x8*)&z_s[(wn + i * 16 + m16) * 256 + gs * 8];
    }

    // ---- GEMM + packed-uint running argmin (no barriers, A+B pipelined)
    unsigned int best[8];
    #pragma unroll
    for (int i = 0; i < 8; i++) best[i] = 0xFFFFFFFFu;

    #pragma unroll 1
    for (int kts = 0; kts < 8; kts++) {
        // prefetch next kt's norms
        float sckn[4];
        const int knext = (((kts + 1) & 7) << 7) + wk;
        #pragma unroll
        for (int j = 0; j < 4; j++) sckn[j] = sc1[knext + j * 16 + m16];

        // acc init = 1 + ||c||^2 (same column k for all 4 regs of a lane)
        f32x4 acc[2][4];
        #pragma unroll
        for (int j = 0; j < 4; j++) {
            f32x4 iv = (f32x4){sck[j], sck[j], sck[j], sck[j]};
            acc[0][j] = iv; acc[1][j] = iv;
        }

        const __bf16* bk  = bbase + (size_t)(kts << 7) * 32;          // this kt, c=0
        const __bf16* bkn = bbase + (size_t)(((kts + 1) & 7) << 7) * 32; // next kt, c=0

        #pragma unroll
        for (int c = 0; c < 8; c++) {
            // prefetch next chunk's B and A
            bf16x8 bn[4], an[2];
            const __bf16* bp = (c == 7) ? bkn : (bk + (size_t)(c + 1) * 32768);
            #pragma unroll
            for (int j = 0; j < 4; j++) bn[j] = *(const bf16x8*)(bp + j * 512);
            const int cn = (c + 1) & 7;
            #pragma unroll
            for (int i = 0; i < 2; i++) {
                int gs = (cn * 4 + q4) ^ (m16 & 7);
                an[i] = *(const bf16x8*)&z_s[(wn + i * 16 + m16) * 256 + gs * 8];
            }

            #pragma unroll
            for (int i = 0; i < 2; i++)
                #pragma unroll
                for (int j = 0; j < 4; j++)
                    acc[i][j] = __builtin_amdgcn_mfma_f32_16x16x32_bf16(a[i], bb[j], acc[i][j], 0, 0, 0);

            #pragma unroll
            for (int j = 0; j < 4; j++) bb[j] = bn[j];
            a[0] = an[0]; a[1] = an[1];
        }

        // epilogue: key = (score_bits & mask) | k ; running uint-min (2 VALU ops/elem)
        #pragma unroll
        for (int j = 0; j < 4; j++) {
            const unsigned int kc = (unsigned int)((kts << 7) + wk + j * 16 + m16);
            #pragma unroll
            for (int i = 0; i < 2; i++)
                #pragma unroll
                for (int r = 0; r < 4; r++) {
                    unsigned int key = (__float_as_uint(acc[i][j][r]) & 0xFFFFFC00u) | kc;
                    best[i * 4 + r] = min(best[i * 4 + r], key);
                }
        }
        #pragma unroll
        for (int j = 0; j < 4; j++) sck[j] = sckn[j];
    }

    // ---- intra-wave min across the 16 col-lanes
    #pragma unroll
    for (int pos = 0; pos < 8; pos++) {
        unsigned int k = best[pos];
        #pragma unroll
        for (int off = 1; off < 16; off <<= 1)
            k = min(k, (unsigned int)__shfl_xor((int)k, off, 64));
        best[pos] = k;
    }
    __syncthreads();              // z_s reads done -> becomes scratch

    // ---- cross-wave combine (2 k-halves per row) in recycled z_s
    unsigned int* ks = (unsigned int*)z_s;   // ks[0..128): key[khalf][row]; ks[128..192): chosen k
    if (m16 == 0) {
        #pragma unroll
        for (int pos = 0; pos < 8; pos++) {
            int i = pos >> 2, r = pos & 3;
            int row = wn + i * 16 + q4 * 4 + r;
            ks[(w & 1) * 64 + row] = best[pos];
        }
    }
    __syncthreads();
    if (t < 64) {
        unsigned int key = min(ks[t], ks[64 + t]);
        int kf = (int)(key & 1023u);
        ks[128 + t] = (unsigned int)kf;
        out[IDX_OFF + n0 + t] = (float)kf;
        lz += __uint_as_float(key & 0xFFFFFC00u) - 1.0f;   // best score, unshifted
    }
    {
        float s = lz;
        #pragma unroll
        for (int off = 1; off < 64; off <<= 1) s += __shfl_xor(s, off, 64);
        if (lane == 0) red_s[w] = s;
    }
    __syncthreads();
    if (t == 0)
        atomicAdd(out + LOSS_OFF, 1.25f * ((red_s[0] + red_s[1]) + (red_s[2] + red_s[3])));

    // ---- stage chosen codebook rows (fp32 source -> bf16), then coalesced emit
    const int qrow = t >> 2;            // 0..63
    const int qoff = (t & 3) * 64;      // 0,64,128,192
    const int myk  = (int)ks[128 + qrow];
    __syncthreads();                    // kf consumed -> safe to overwrite z_s
    {
        const float* qp = cb + (size_t)myk * 256 + qoff;
        #pragma unroll
        for (int p = 0; p < 8; p++) {
            float4 f0 = *(const float4*)(qp + p * 8);
            float4 f1 = *(const float4*)(qp + p * 8 + 4);
            bf16x8 v;
            v[0]=(__bf16)f0.x; v[1]=(__bf16)f0.y; v[2]=(__bf16)f0.z; v[3]=(__bf16)f0.w;
            v[4]=(__bf16)f1.x; v[5]=(__bf16)f1.y; v[6]=(__bf16)f1.z; v[7]=(__bf16)f1.w;
            int gs = ((qoff >> 3) + p) ^ (qrow & 7);
            *(bf16x8*)&z_s[qrow * 256 + gs * 8] = v;
        }
    }
    __syncthreads();
    {
        const int nl = t & 63;
        const int dq = (t >> 6) << 6;
        float* op = out + (size_t)(b * 256 + dq) * 1024 + hw0 + nl;
        #pragma unroll
        for (int p = 0; p < 8; p++) {
            int gs = ((dq >> 3) + p) ^ (nl & 7);
            bf16x8 v = *(const bf16x8*)&z_s[nl * 256 + gs * 8];
            #pragma unroll
            for (int j = 0; j < 8; j++)
                op[(size_t)(p * 8 + j) * 1024] = (float)v[j];
        }
    }
}

extern "C" void kernel_launch(void* const* d_in, const int* in_sizes, int n_in,
                              void* d_out, int out_size, void* d_ws, size_t ws_size,
                              hipStream_t stream) {
    const float* z  = (const float*)d_in[0];   // 16777216
    const float* cb = (const float*)d_in[1];   // 262144
    float* out = (float*)d_out;

    float*  sc1 = (float*)d_ws;                        // 1024 f  (1 + ||c||^2)
    __bf16* cbh = (__bf16*)((char*)d_ws + 8192);       // 512 KB transposed bf16 codebook

    vq_prep<<<64, 256, 0, stream>>>(cb, cbh, sc1, out);
    vq_mfma<<<1024, 256, 0, stream>>>(z, cb, cbh, sc1, out);
}